// Round 1
// baseline (5242.728 us; speedup 1.0000x reference)
//
#include <hip/hip_runtime.h>

// NoPropCTMomentNet: 10-step Euler integration of a 17->64->64->32->8 swish MLP.
// Round 1: fp32 VALU baseline. One thread = one row; all activations in VGPRs;
// weights are wave-uniform -> scalar loads (SGPR operands to v_fmac).

constexpr int NSTEP = 10;

__device__ __forceinline__ float swish(float x) {
    // x * sigmoid(x); v_exp_f32 + v_rcp_f32 (accuracy ~1ulp, far under 0.1125 absmax budget)
    float s = __builtin_amdgcn_rcpf(1.0f + __expf(-x));
    return x * s;
}

__global__ __launch_bounds__(256) void noprop_f32_kernel(
    const float* __restrict__ eta,
    const float* __restrict__ W1, const float* __restrict__ b1,
    const float* __restrict__ W2, const float* __restrict__ b2,
    const float* __restrict__ W3, const float* __restrict__ b3,
    const float* __restrict__ W4, const float* __restrict__ b4,
    float* __restrict__ out, int batch)
{
    const int row = blockIdx.x * blockDim.x + threadIdx.x;
    if (row >= batch) return;
    const float dt = 0.1f;

    float et[8], st[8];
    {
        const float4* ep = reinterpret_cast<const float4*>(eta + (size_t)row * 8);
        float4 a = ep[0], b = ep[1];
        et[0] = a.x; et[1] = a.y; et[2] = a.z; et[3] = a.w;
        et[4] = b.x; et[5] = b.y; et[6] = b.z; et[7] = b.w;
    }
#pragma unroll
    for (int i = 0; i < 8; ++i) st[i] = et[i];

#pragma unroll 1
    for (int step = 0; step < NSTEP; ++step) {
        const float t = dt * (float)step;

        // ---- layer 1: x = [st(8), et(8), t] @ W1[17,64] + b1, swish
        float h1[64];
#pragma unroll
        for (int j = 0; j < 64; ++j) h1[j] = fmaf(t, W1[16 * 64 + j], b1[j]);
#pragma unroll 1
        for (int i = 0; i < 8; ++i) {
            const float xs = st[i];
            const float xe = et[i];
            const float* __restrict__ ws = W1 + i * 64;
            const float* __restrict__ we = W1 + (i + 8) * 64;
#pragma unroll
            for (int j = 0; j < 64; ++j) h1[j] = fmaf(xs, ws[j], h1[j]);
#pragma unroll
            for (int j = 0; j < 64; ++j) h1[j] = fmaf(xe, we[j], h1[j]);
        }
#pragma unroll
        for (int j = 0; j < 64; ++j) h1[j] = swish(h1[j]);

        // ---- layer 2: h1[64] @ W2[64,64] + b2, swish
        float h2[64];
#pragma unroll
        for (int j = 0; j < 64; ++j) h2[j] = b2[j];
#pragma unroll 2
        for (int i = 0; i < 64; ++i) {
            const float x = h1[i];
            const float* __restrict__ w = W2 + i * 64;
#pragma unroll
            for (int j = 0; j < 64; ++j) h2[j] = fmaf(x, w[j], h2[j]);
        }
#pragma unroll
        for (int j = 0; j < 64; ++j) h2[j] = swish(h2[j]);

        // ---- layer 3: h2[64] @ W3[64,32] + b3, swish
        float h3[32];
#pragma unroll
        for (int j = 0; j < 32; ++j) h3[j] = b3[j];
#pragma unroll 2
        for (int i = 0; i < 64; ++i) {
            const float x = h2[i];
            const float* __restrict__ w = W3 + i * 32;
#pragma unroll
            for (int j = 0; j < 32; ++j) h3[j] = fmaf(x, w[j], h3[j]);
        }
#pragma unroll
        for (int j = 0; j < 32; ++j) h3[j] = swish(h3[j]);

        // ---- layer 4: h3[32] @ W4[32,8] + b4; Euler update
        float o[8];
#pragma unroll
        for (int j = 0; j < 8; ++j) o[j] = b4[j];
#pragma unroll 4
        for (int i = 0; i < 32; ++i) {
            const float x = h3[i];
            const float* __restrict__ w = W4 + i * 8;
#pragma unroll
            for (int j = 0; j < 8; ++j) o[j] = fmaf(x, w[j], o[j]);
        }
#pragma unroll
        for (int j = 0; j < 8; ++j) st[j] = fmaf(dt, o[j], st[j]);
    }

    float4 o0 = make_float4(st[0], st[1], st[2], st[3]);
    float4 o1 = make_float4(st[4], st[5], st[6], st[7]);
    float4* op = reinterpret_cast<float4*>(out + (size_t)row * 8);
    op[0] = o0;
    op[1] = o1;
}

extern "C" void kernel_launch(void* const* d_in, const int* in_sizes, int n_in,
                              void* d_out, int out_size, void* d_ws, size_t ws_size,
                              hipStream_t stream) {
    const float* eta = (const float*)d_in[0];
    const float* W1  = (const float*)d_in[1];
    const float* b1  = (const float*)d_in[2];
    const float* W2  = (const float*)d_in[3];
    const float* b2  = (const float*)d_in[4];
    const float* W3  = (const float*)d_in[5];
    const float* b3  = (const float*)d_in[6];
    const float* W4  = (const float*)d_in[7];
    const float* b4  = (const float*)d_in[8];
    float* out = (float*)d_out;

    const int batch = in_sizes[0] / 8;
    const int block = 256;
    const int grid = (batch + block - 1) / block;
    hipLaunchKernelGGL(noprop_f32_kernel, dim3(grid), dim3(block), 0, stream,
                       eta, W1, b1, W2, b2, W3, b3, W4, b4, out, batch);
}